// Round 15
// baseline (321.996 us; speedup 1.0000x reference)
//
#include <hip/hip_runtime.h>
#include <math.h>

#define N_NODES 50000
#define N_EDGES 800000
#define ETOT    (N_EDGES + N_NODES)
#define EPAD_MAX 1200000
#define IN_CH   128
#define OUT_CH  40
#define NEG     0.2f
#define CAP     64         // max cached slots per node (Poisson(17) max ~48)

// single-level bucketed CSR
#define NPF   98           // nodes per fine partition
#define NFINE 512          // 512*98 = 50176 >= 50000
#define FCAP  2400         // capacity per fine (mean ~1666, +5 sigma ~1870)

typedef __attribute__((ext_vector_type(8))) short bf16x8;
typedef __attribute__((ext_vector_type(4))) float f32x4;
typedef __attribute__((ext_vector_type(2))) float f32x2;

__device__ inline unsigned short f2bf(float f) {
    unsigned int u = __float_as_uint(f);
    return (unsigned short)((u + 0x7FFFu + ((u >> 16) & 1u)) >> 16);
}
__device__ inline float bf2f(unsigned short u) {
    return __uint_as_float((unsigned int)u << 16);
}
__device__ inline float lrelu(float a) { return (a > 0.f) ? a : NEG * a; }

// ---------------------------------------------------------------------------
// Single-pass bucketing into 512 fine partitions + fused weight transposes.
// Blocks [0,256): bucket edges. Blocks [256,704): weight transpose.
// ---------------------------------------------------------------------------
__global__ __launch_bounds__(256) void k_bkt(const int* __restrict__ ei,
                                             int* __restrict__ fcur,
                                             unsigned int* __restrict__ fbuf,
                                             const float* __restrict__ W1,
                                             const float* __restrict__ W2,
                                             const float* __restrict__ W3,
                                             unsigned short* __restrict__ Wt1,
                                             unsigned short* __restrict__ Wt2,
                                             unsigned short* __restrict__ Wt3) {
    if (blockIdx.x >= 256) {
        int i = (blockIdx.x - 256) * 256 + threadIdx.x;
        if (i < 32768) {                       // W1: 256 x 128
            int n = i >> 7, k = i & 127;
            Wt1[i] = f2bf(W1[(long)k * 256 + n]);
        } else if (i < 98304) {                // W2: 256 x 256
            int j = i - 32768;
            int n = j >> 8, k = j & 255;
            Wt2[j] = f2bf(W2[(long)k * 256 + n]);
        } else if (i < 114688) {               // W3: 64(pad) x 256
            int j = i - 98304;
            int n = j >> 8, k = j & 255;
            Wt3[j] = (n < OUT_CH) ? f2bf(W3[(long)k * OUT_CH + n]) : (unsigned short)0;
        }
        return;
    }
    __shared__ int lcnt[NFINE], lbase[NFINE], lcur[NFINE];
    int tid = threadIdx.x;
    for (int i = tid; i < NFINE; i += 256) lcnt[i] = 0;
    __syncthreads();
    for (int i = blockIdx.x * 256 + tid; i < ETOT; i += 256 * 256) {
        int d = (i < N_EDGES) ? ei[N_EDGES + i] : (i - N_EDGES);
        atomicAdd(&lcnt[d / NPF], 1);
    }
    __syncthreads();
    for (int i = tid; i < NFINE; i += 256) {
        lbase[i] = atomicAdd(&fcur[i], lcnt[i]);
        lcur[i] = 0;
    }
    __syncthreads();
    for (int i = blockIdx.x * 256 + tid; i < ETOT; i += 256 * 256) {
        int s, d;
        if (i < N_EDGES) { s = ei[i]; d = ei[N_EDGES + i]; }
        else             { s = i - N_EDGES; d = s; }
        int p = d / NPF;
        int off = atomicAdd(&lcur[p], 1);
        fbuf[(long)p * FCAP + lbase[p] + off] = (unsigned int)s | ((unsigned int)d << 16);
    }
}

// Degrees via LDS counting: one block per fine partition.
__global__ __launch_bounds__(256) void k_deg(const int* __restrict__ fcur,
                                             const unsigned int* __restrict__ fbuf,
                                             int* __restrict__ deg) {
    __shared__ int cnt[NPF];
    int f = blockIdx.x;
    int tid = threadIdx.x;
    int n0 = f * NPF;
    int nend = min(n0 + NPF, N_NODES);
    if (tid < NPF) cnt[tid] = 0;
    __syncthreads();
    int n = fcur[f];
    for (int i = tid; i < n; i += 256)
        atomicAdd(&cnt[(int)(fbuf[(long)f * FCAP + i] >> 16) - n0], 1);
    __syncthreads();
    if (tid < NPF && n0 + tid < nend) deg[n0 + tid] = cnt[tid];
}

__global__ void k_scan1(const int* __restrict__ deg, int* __restrict__ start,
                        int* __restrict__ bsum) {
    __shared__ int sh[256];
    int tid = threadIdx.x;
    int i = blockIdx.x * 256 + tid;
    int v = (i < N_NODES) ? ((deg[i] + 7) & ~7) : 0;
    int x = v;
    sh[tid] = x;
    __syncthreads();
    #pragma unroll
    for (int off = 1; off < 256; off <<= 1) {
        int t = (tid >= off) ? sh[tid - off] : 0;
        __syncthreads();
        x += t;
        sh[tid] = x;
        __syncthreads();
    }
    if (i < N_NODES) start[i] = x - v;
    if (tid == 255) bsum[blockIdx.x] = x;
}

// merged scan2+scan3
__global__ void k_scan3(int* __restrict__ start, const int* __restrict__ bsum,
                        int nb) {
    __shared__ int sh[256];
    __shared__ int ex[256];
    int tid = threadIdx.x;
    int v = (tid < nb) ? bsum[tid] : 0;
    int x = v;
    sh[tid] = x;
    __syncthreads();
    #pragma unroll
    for (int off = 1; off < 256; off <<= 1) {
        int t = (tid >= off) ? sh[tid - off] : 0;
        __syncthreads();
        x += t;
        sh[tid] = x;
        __syncthreads();
    }
    ex[tid] = x - v;
    __syncthreads();
    int add = ex[blockIdx.x];
    int i = blockIdx.x * 256 + tid;
    if (i < N_NODES) start[i] += add;
}

// Final scatter + pad fill: one block per fine partition.
__global__ __launch_bounds__(256) void k_scat(const int* __restrict__ fcur,
                                              const unsigned int* __restrict__ fbuf,
                                              const int* __restrict__ start,
                                              int* __restrict__ eSrc) {
    __shared__ int offs[NPF];
    __shared__ int base[NPF];
    int f = blockIdx.x;
    int tid = threadIdx.x;
    int n0 = f * NPF;
    int nend = min(n0 + NPF, N_NODES);
    int nn = nend - n0;
    if (tid < NPF && tid < nn) {
        int b = start[n0 + tid];
        offs[tid] = b;
        base[tid] = b;
    }
    __syncthreads();
    int n = fcur[f];
    for (int i = tid; i < n; i += 256) {
        unsigned int u = fbuf[(long)f * FCAP + i];
        int d = (int)(u >> 16);
        int pos = atomicAdd(&offs[d - n0], 1);
        eSrc[pos] = (int)(u & 0xFFFFu);
    }
    __syncthreads();
    if (tid < NPF && tid < nn) {
        int endp = offs[tid];
        int dg = endp - base[tid];
        int stop = base[tid] + ((dg + 7) & ~7);
        for (int k2 = endp; k2 < stop; ++k2) eSrc[k2] = -1;
    }
}

// ---------------------------------------------------------------------------
// bf16 MFMA GEMM with fused attention logits (unchanged from R14).
// ---------------------------------------------------------------------------
#define PITCH 40
template<int BN, int FM, int FN, bool CVT, bool FP8OUT, bool L4>
__global__ __launch_bounds__(256) void k_mfma(const void* __restrict__ Araw,
                                              const unsigned short* __restrict__ Bt,
                                              void* __restrict__ Cout,
                                              const float* __restrict__ a_s,
                                              const float* __restrict__ a_d,
                                              float* __restrict__ als,
                                              float* __restrict__ ald,
                                              int M, int K, int Ncol) {
    __shared__ unsigned short As[128 * PITCH];
    __shared__ unsigned short Bs[BN * PITCH];
    const int WCOLS = BN / (FN * 16);
    int tid = threadIdx.x;
    int wave = tid >> 6, lane = tid & 63;
    int quad = lane >> 4, l16 = lane & 15;
    int wr = wave / WCOLS, wc = wave % WCOLS;
    long row0 = (long)blockIdx.x * 128;
    int col0 = blockIdx.y * BN;

    f32x4 acc[FM][FN] = {};

    for (int k0 = 0; k0 < K; k0 += 32) {
        for (int c = tid; c < 512; c += 256) {
            int r = c >> 2, kp = (c & 3) << 3;
            long gr = row0 + r;
            if (CVT) {
                const float* A32 = (const float*)Araw;
                ushort4 lo = {0,0,0,0}, hi = {0,0,0,0};
                if (gr < M) {
                    float4 v0 = *(const float4*)(A32 + gr * K + k0 + kp);
                    float4 v1 = *(const float4*)(A32 + gr * K + k0 + kp + 4);
                    lo.x = f2bf(v0.x); lo.y = f2bf(v0.y); lo.z = f2bf(v0.z); lo.w = f2bf(v0.w);
                    hi.x = f2bf(v1.x); hi.y = f2bf(v1.y); hi.z = f2bf(v1.z); hi.w = f2bf(v1.w);
                }
                *(ushort4*)(As + r * PITCH + kp) = lo;
                *(ushort4*)(As + r * PITCH + kp + 4) = hi;
            } else {
                const unsigned short* A16 = (const unsigned short*)Araw;
                uint4 v = {0u, 0u, 0u, 0u};
                if (gr < M) v = *(const uint4*)(A16 + gr * K + k0 + kp);
                *(uint4*)(As + r * PITCH + kp) = v;
            }
        }
        for (int c = tid; c < BN * 4; c += 256) {
            int r = c >> 2, kp = (c & 3) << 3;
            uint4 v = *(const uint4*)(Bt + (long)(col0 + r) * K + k0 + kp);
            *(uint4*)(Bs + r * PITCH + kp) = v;
        }
        __syncthreads();
        bf16x8 af[FM], bfr[FN];
        #pragma unroll
        for (int i = 0; i < FM; ++i)
            af[i] = *(const bf16x8*)(As + (wr * FM * 16 + i * 16 + l16) * PITCH + quad * 8);
        #pragma unroll
        for (int j = 0; j < FN; ++j)
            bfr[j] = *(const bf16x8*)(Bs + (wc * FN * 16 + j * 16 + l16) * PITCH + quad * 8);
        #pragma unroll
        for (int i = 0; i < FM; ++i)
            #pragma unroll
            for (int j = 0; j < FN; ++j)
                acc[i][j] = __builtin_amdgcn_mfma_f32_16x16x32_bf16(af[i], bfr[j], acc[i][j], 0, 0, 0);
        __syncthreads();
    }

    // fused logits
    {
        int head = L4 ? (blockIdx.y * WCOLS + wc) : 0;
        float as_v[FN], ad_v[FN];
        #pragma unroll
        for (int j = 0; j < FN; ++j) {
            int cidx = j * 16 + l16;
            if (L4) {
                as_v[j] = a_s[head * 64 + cidx];
                ad_v[j] = a_d[head * 64 + cidx];
            } else {
                as_v[j] = (cidx < OUT_CH) ? a_s[cidx] : 0.f;
                ad_v[j] = (cidx < OUT_CH) ? a_d[cidx] : 0.f;
            }
        }
        #pragma unroll
        for (int i = 0; i < FM; ++i) {
            #pragma unroll
            for (int v = 0; v < 4; ++v) {
                float ps = acc[i][0][v] * as_v[0] + acc[i][1][v] * as_v[1]
                         + acc[i][2][v] * as_v[2] + acc[i][3][v] * as_v[3];
                float pd = acc[i][0][v] * ad_v[0] + acc[i][1][v] * ad_v[1]
                         + acc[i][2][v] * ad_v[2] + acc[i][3][v] * ad_v[3];
                #pragma unroll
                for (int off = 1; off < 16; off <<= 1) {
                    ps += __shfl_xor(ps, off);
                    pd += __shfl_xor(pd, off);
                }
                if (l16 == 0) {
                    long row = row0 + wr * (FM * 16) + i * 16 + quad * 4 + v;
                    if (row < M) {
                        if (L4) { als[row * 4 + head] = ps; ald[row * 4 + head] = pd; }
                        else    { als[row] = ps; ald[row] = pd; }
                    }
                }
            }
        }
    }

    if (FP8OUT) {
        unsigned char* C8 = (unsigned char*)Cout;
        #pragma unroll
        for (int i = 0; i < FM; ++i) {
            #pragma unroll
            for (int v = 0; v < 4; ++v) {
                long row = row0 + wr * FM * 16 + i * 16 + quad * 4 + v;
                if (row < M) {
                    int p01 = __builtin_amdgcn_cvt_pk_fp8_f32(acc[i][0][v], acc[i][1][v], 0, false);
                    int p23 = __builtin_amdgcn_cvt_pk_fp8_f32(acc[i][2][v], acc[i][3][v], 0, false);
                    unsigned char* b = C8 + row * 256 + col0 + wc * (FN * 16) + l16;
                    b[0]  = (unsigned char)(p01 & 0xFF);
                    b[16] = (unsigned char)((p01 >> 8) & 0xFF);
                    b[32] = (unsigned char)(p23 & 0xFF);
                    b[48] = (unsigned char)((p23 >> 8) & 0xFF);
                }
            }
        }
    } else {
        unsigned short* C = (unsigned short*)Cout;
        #pragma unroll
        for (int i = 0; i < FM; ++i) {
            long rowb = row0 + wr * FM * 16 + i * 16 + quad * 4;
            #pragma unroll
            for (int j = 0; j < FN; ++j) {
                int col = col0 + wc * FN * 16 + j * 16 + l16;
                if (col < Ncol) {
                    #pragma unroll
                    for (int v = 0; v < 4; ++v) {
                        long r = rowb + v;
                        if (r < M) C[r * Ncol + col] = f2bf(acc[i][j][v]);
                    }
                }
            }
        }
    }
}

// ---------------------------------------------------------------------------
// Aggregation (4-head), fp8 gather, TWO waves per node. Each wave owns half
// the slot range (phase 1 + phase 2 wave-private); cross-wave combine via LDS.
// Block = 4 waves = 2 nodes.
// ---------------------------------------------------------------------------
__global__ __launch_bounds__(256) void k_agg4(const unsigned char* __restrict__ h8,
                                              const int* __restrict__ start,
                                              const int* __restrict__ deg,
                                              const int* __restrict__ eSrc,
                                              const float* __restrict__ als,
                                              const float* __restrict__ ald,
                                              const float* __restrict__ bias,
                                              unsigned short* __restrict__ out) {
    __shared__ float wbuf[2][CAP * 4];
    __shared__ int   sbuf[2][CAP];
    __shared__ float red[2][32][9];
    int tid = threadIdx.x;
    int wave = tid >> 6;
    int nib = wave >> 1;         // node in block
    int sub = wave & 1;          // which wave of the node
    int node = blockIdx.x * 2 + nib;
    int lane = tid & 63;
    // grid sized so node < N_NODES always (N even)

    int st = start[node];
    int dgp = (deg[node] + 7) & ~7;
    const int* ep = eSrc + st;
    int ncap = (dgp < CAP) ? dgp : CAP;
    int hc = ((ncap >> 1) + 7) & ~7;     // split point, mult of 8
    if (hc > ncap) hc = ncap;
    int lo = sub ? hc : 0;
    int hi = sub ? ncap : hc;

    // ---- phase 1: weights for this wave's range (wave-private) ----
    int l16 = lane & 15, headw = lane >> 4;
    float aldd4 = ald[node * 4 + headw];
    for (int c = lo; c < hi; c += 16) {
        int slot = c + l16;
        bool ok = (slot < hi);
        int raw = ok ? ep[slot] : -1;
        int ss = (raw < 0) ? 0 : raw;
        float a = als[(long)ss * 4 + headw] + aldd4;
        float w = (raw < 0) ? 0.f : __expf(lrelu(a));
        if (ok) {
            wbuf[nib][slot * 4 + headw] = w;
            if (headw == 0) sbuf[nib][slot] = ss;
        }
    }

    // ---- phase 2: half-wave per edge over this wave's range ----
    int half = lane >> 5;
    int hl = lane & 31;
    int head8 = hl >> 3;
    float den = 0.f;
    f32x2 acc2[4] = {};

    int pairs = (hi - lo) >> 1;          // mult of 4 (or 0)
    for (int pi = 0; pi < pairs; pi += 4) {
        int s[4];
        float w[4];
        #pragma unroll
        for (int u = 0; u < 4; ++u) {
            int slot = lo + (pi + u) * 2 + half;
            s[u] = sbuf[nib][slot];
            w[u] = wbuf[nib][slot * 4 + head8];
        }
        uint2 hv[4];
        #pragma unroll
        for (int u = 0; u < 4; ++u)
            hv[u] = *(const uint2*)(h8 + (long)s[u] * 256 + hl * 8);
        #pragma unroll
        for (int u = 0; u < 4; ++u) {
            den += w[u];
            f32x2 w2; w2.x = w[u]; w2.y = w[u];
            acc2[0] += w2 * __builtin_amdgcn_cvt_pk_f32_fp8((int)hv[u].x, false);
            acc2[1] += w2 * __builtin_amdgcn_cvt_pk_f32_fp8((int)hv[u].x, true);
            acc2[2] += w2 * __builtin_amdgcn_cvt_pk_f32_fp8((int)hv[u].y, false);
            acc2[3] += w2 * __builtin_amdgcn_cvt_pk_f32_fp8((int)hv[u].y, true);
        }
    }

    // ---- overflow beyond CAP (sub==1 only; practically never taken) ----
    if (sub == 1 && dgp > ncap) {
        float aldd8 = ald[node * 4 + head8];
        for (int j = ncap; j < dgp; j += 2) {
            int raw = ep[j + half];
            int ss = (raw < 0) ? 0 : raw;
            float w = (raw < 0) ? 0.f : __expf(lrelu(als[(long)ss * 4 + head8] + aldd8));
            uint2 hv = *(const uint2*)(h8 + (long)ss * 256 + hl * 8);
            den += w;
            f32x2 w2; w2.x = w; w2.y = w;
            acc2[0] += w2 * __builtin_amdgcn_cvt_pk_f32_fp8((int)hv.x, false);
            acc2[1] += w2 * __builtin_amdgcn_cvt_pk_f32_fp8((int)hv.x, true);
            acc2[2] += w2 * __builtin_amdgcn_cvt_pk_f32_fp8((int)hv.y, false);
            acc2[3] += w2 * __builtin_amdgcn_cvt_pk_f32_fp8((int)hv.y, true);
        }
    }

    // ---- in-wave half combine ----
    den += __shfl_xor(den, 32);
    #pragma unroll
    for (int c = 0; c < 4; ++c) {
        acc2[c].x += __shfl_xor(acc2[c].x, 32);
        acc2[c].y += __shfl_xor(acc2[c].y, 32);
    }

    // ---- cross-wave combine via LDS ----
    if (sub == 1 && half == 0) {
        #pragma unroll
        for (int c = 0; c < 4; ++c) {
            red[nib][hl][c * 2]     = acc2[c].x;
            red[nib][hl][c * 2 + 1] = acc2[c].y;
        }
        red[nib][hl][8] = den;
    }
    __syncthreads();
    if (sub == 0 && half == 0) {
        #pragma unroll
        for (int c = 0; c < 4; ++c) {
            acc2[c].x += red[nib][hl][c * 2];
            acc2[c].y += red[nib][hl][c * 2 + 1];
        }
        den += red[nib][hl][8];

        float inv = 1.f / den;
        int cb = hl * 8;
        float4 b0 = *(const float4*)(bias + cb);
        float4 b1 = *(const float4*)(bias + cb + 4);
        float v0 = fmaxf(acc2[0].x * inv + b0.x, 0.f);
        float v1 = fmaxf(acc2[0].y * inv + b0.y, 0.f);
        float v2 = fmaxf(acc2[1].x * inv + b0.z, 0.f);
        float v3 = fmaxf(acc2[1].y * inv + b0.w, 0.f);
        float v4 = fmaxf(acc2[2].x * inv + b1.x, 0.f);
        float v5 = fmaxf(acc2[2].y * inv + b1.y, 0.f);
        float v6 = fmaxf(acc2[3].x * inv + b1.z, 0.f);
        float v7 = fmaxf(acc2[3].y * inv + b1.w, 0.f);
        uint4 o;
        o.x = (unsigned int)f2bf(v0) | ((unsigned int)f2bf(v1) << 16);
        o.y = (unsigned int)f2bf(v2) | ((unsigned int)f2bf(v3) << 16);
        o.z = (unsigned int)f2bf(v4) | ((unsigned int)f2bf(v5) << 16);
        o.w = (unsigned int)f2bf(v6) | ((unsigned int)f2bf(v7) << 16);
        *(uint4*)(out + (long)node * 256 + cb) = o;
    }
}

// ---------------------------------------------------------------------------
// Final layer agg: quad-per-edge, 16-slot unroll, fused weights + bias +
// log_softmax (unchanged from R14).
// ---------------------------------------------------------------------------
__global__ __launch_bounds__(256) void k_agg1(const unsigned short* __restrict__ h,
                                              const int* __restrict__ start,
                                              const int* __restrict__ deg,
                                              const int* __restrict__ eSrc,
                                              const float* __restrict__ als,
                                              const float* __restrict__ ald,
                                              const float* __restrict__ bias,
                                              float* __restrict__ out) {
    int node = (blockIdx.x * blockDim.x + threadIdx.x) >> 6;
    int lane = threadIdx.x & 63;
    if (node >= N_NODES) return;
    int q = lane >> 4, r = lane & 15;
    bool act = (r < 10);
    int st = start[node];
    int dgp = (deg[node] + 7) & ~7;
    const int* ep = eSrc + st;
    float aldd = ald[node];

    float den = 0.f;
    float4 acc = {0.f, 0.f, 0.f, 0.f};

    int j = 0;
    for (; j + 16 <= dgp; j += 16) {
        int base = j + q * 4;
        int s[4];
        float w[4];
        #pragma unroll
        for (int u = 0; u < 4; ++u) s[u] = ep[base + u];
        #pragma unroll
        for (int u = 0; u < 4; ++u) {
            int raw = s[u];
            int ss = (raw < 0) ? 0 : raw;
            w[u] = (raw < 0) ? 0.f : __expf(lrelu(als[ss] + aldd));
            s[u] = ss;
        }
        ushort4 hh[4];
        #pragma unroll
        for (int u = 0; u < 4; ++u) {
            ushort4 t = {0, 0, 0, 0};
            if (act) t = *(const ushort4*)(h + (long)s[u] * OUT_CH + r * 4);
            hh[u] = t;
        }
        #pragma unroll
        for (int u = 0; u < 4; ++u) {
            den += w[u];
            acc.x += w[u] * bf2f(hh[u].x);
            acc.y += w[u] * bf2f(hh[u].y);
            acc.z += w[u] * bf2f(hh[u].z);
            acc.w += w[u] * bf2f(hh[u].w);
        }
    }
    if (j < dgp) {
        int base = j + q * 2;
        int s[2];
        float w[2];
        #pragma unroll
        for (int u = 0; u < 2; ++u) s[u] = ep[base + u];
        #pragma unroll
        for (int u = 0; u < 2; ++u) {
            int raw = s[u];
            int ss = (raw < 0) ? 0 : raw;
            w[u] = (raw < 0) ? 0.f : __expf(lrelu(als[ss] + aldd));
            s[u] = ss;
        }
        ushort4 hh[2];
        #pragma unroll
        for (int u = 0; u < 2; ++u) {
            ushort4 t = {0, 0, 0, 0};
            if (act) t = *(const ushort4*)(h + (long)s[u] * OUT_CH + r * 4);
            hh[u] = t;
        }
        #pragma unroll
        for (int u = 0; u < 2; ++u) {
            den += w[u];
            acc.x += w[u] * bf2f(hh[u].x);
            acc.y += w[u] * bf2f(hh[u].y);
            acc.z += w[u] * bf2f(hh[u].z);
            acc.w += w[u] * bf2f(hh[u].w);
        }
    }

    #pragma unroll
    for (int off = 16; off < 64; off <<= 1) {
        acc.x += __shfl_xor(acc.x, off);
        acc.y += __shfl_xor(acc.y, off);
        acc.z += __shfl_xor(acc.z, off);
        acc.w += __shfl_xor(acc.w, off);
        den   += __shfl_xor(den, off);
    }
    float inv = 1.f / den;
    float4 bv = {0.f, 0.f, 0.f, 0.f};
    if (act) bv = *(const float4*)(bias + r * 4);
    float4 v;
    v.x = acc.x * inv + bv.x;
    v.y = acc.y * inv + bv.y;
    v.z = acc.z * inv + bv.z;
    v.w = acc.w * inv + bv.w;
    float mx = act ? fmaxf(fmaxf(v.x, v.y), fmaxf(v.z, v.w)) : -INFINITY;
    #pragma unroll
    for (int off = 1; off < 16; off <<= 1) mx = fmaxf(mx, __shfl_xor(mx, off));
    float sum = act ? (__expf(v.x - mx) + __expf(v.y - mx) + __expf(v.z - mx) + __expf(v.w - mx)) : 0.f;
    #pragma unroll
    for (int off = 1; off < 16; off <<= 1) sum += __shfl_xor(sum, off);
    float lse = mx + logf(sum);
    if (q == 0 && act) {
        float4 o;
        o.x = v.x - lse;
        o.y = v.y - lse;
        o.z = v.z - lse;
        o.w = v.w - lse;
        *(float4*)(out + (long)node * OUT_CH + r * 4) = o;
    }
}

// ---------------------------------------------------------------------------
extern "C" void kernel_launch(void* const* d_in, const int* in_sizes, int n_in,
                              void* d_out, int out_size, void* d_ws, size_t ws_size,
                              hipStream_t stream) {
    (void)in_sizes; (void)n_in; (void)out_size; (void)ws_size;
    const float* x   = (const float*)d_in[0];
    const int*   ei  = (const int*)d_in[1];
    const float* W1  = (const float*)d_in[2];
    const float* as1 = (const float*)d_in[3];
    const float* ad1 = (const float*)d_in[4];
    const float* b1  = (const float*)d_in[5];
    const float* W2  = (const float*)d_in[6];
    const float* as2 = (const float*)d_in[7];
    const float* ad2 = (const float*)d_in[8];
    const float* b2  = (const float*)d_in[9];
    const float* W3  = (const float*)d_in[10];
    const float* as3 = (const float*)d_in[11];
    const float* ad3 = (const float*)d_in[12];
    const float* b3  = (const float*)d_in[13];
    float* out = (float*)d_out;

    char* p = (char*)d_ws;
    auto alloc = [&](size_t b) { char* r = p; p += (b + 255) & ~(size_t)255; return r; };
    int*   deg   = (int*)alloc((size_t)N_NODES * 4);
    int*   start = (int*)alloc((size_t)N_NODES * 4);
    int*   bsum  = (int*)alloc(256 * 4);
    int*   fcur  = (int*)alloc((size_t)NFINE * 4);
    unsigned int* fbuf = (unsigned int*)alloc((size_t)NFINE * FCAP * 4);
    int*   eSrc  = (int*)alloc((size_t)EPAD_MAX * 4);
    float* als   = (float*)alloc((size_t)N_NODES * 4 * 4);
    float* ald   = (float*)alloc((size_t)N_NODES * 4 * 4);
    unsigned char*  hA8  = (unsigned char*)alloc((size_t)N_NODES * 256);
    unsigned short* hBbf = (unsigned short*)alloc((size_t)N_NODES * 256 * 2);
    unsigned short* h3bf = (unsigned short*)alloc((size_t)N_NODES * OUT_CH * 2);
    unsigned short* Wt1  = (unsigned short*)alloc((size_t)256 * IN_CH * 2);
    unsigned short* Wt2  = (unsigned short*)alloc((size_t)256 * 256 * 2);
    unsigned short* Wt3  = (unsigned short*)alloc((size_t)64 * 256 * 2);

    const int NB = (N_NODES + 255) / 256;
    const int WB = (N_NODES + 3) / 4;
    const int AB = N_NODES / 2;            // agg4: 2 nodes/block
    const int MB = (N_NODES + 127) / 128;

    // ---- CSR build + weight transpose (fused grid) ----
    hipMemsetAsync(fcur, 0, (size_t)NFINE * 4, stream);
    k_bkt<<<256 + 448, 256, 0, stream>>>(ei, fcur, fbuf, W1, W2, W3, Wt1, Wt2, Wt3);
    k_deg<<<NFINE, 256, 0, stream>>>(fcur, fbuf, deg);
    k_scan1<<<NB, 256, 0, stream>>>(deg, start, bsum);
    k_scan3<<<NB, 256, 0, stream>>>(start, bsum, NB);
    k_scat<<<NFINE, 256, 0, stream>>>(fcur, fbuf, start, eSrc);

    // ---- layer 1 (fp32 in, fp8 out, fused logits) ----
    k_mfma<128, 4, 4, true, true, true><<<dim3(MB, 2), 256, 0, stream>>>(
        x, Wt1, hA8, as1, ad1, als, ald, N_NODES, IN_CH, 256);
    k_agg4<<<AB, 256, 0, stream>>>(hA8, start, deg, eSrc, als, ald, b1, hBbf);

    // ---- layer 2 (bf16 in, fp8 out, fused logits) ----
    k_mfma<128, 4, 4, false, true, true><<<dim3(MB, 2), 256, 0, stream>>>(
        hBbf, Wt2, hA8, as2, ad2, als, ald, N_NODES, 256, 256);
    k_agg4<<<AB, 256, 0, stream>>>(hA8, start, deg, eSrc, als, ald, b2, hBbf);

    // ---- layer 3 (bf16 in, bf16 out, fused single-head logits) ----
    k_mfma<64, 2, 4, false, false, false><<<dim3(MB, 1), 256, 0, stream>>>(
        hBbf, Wt3, h3bf, as3, ad3, als, ald, N_NODES, 256, OUT_CH);
    k_agg1<<<WB, 256, 0, stream>>>(h3bf, start, deg, eSrc, als, ald, b3, out);
}

// Round 16
// 317.149 us; speedup vs baseline: 1.0153x; 1.0153x over previous
//
#include <hip/hip_runtime.h>
#include <math.h>

#define N_NODES 50000
#define N_EDGES 800000
#define ETOT    (N_EDGES + N_NODES)
#define EPAD_MAX 1200000
#define IN_CH   128
#define OUT_CH  40
#define NEG     0.2f
#define CAP     64         // max cached slots per node (Poisson(17) max ~48)

// single-level bucketed CSR
#define NPF   98           // nodes per fine partition
#define NFINE 512          // 512*98 = 50176 >= 50000
#define FCAP  2400         // capacity per fine (mean ~1666)

typedef __attribute__((ext_vector_type(8))) short bf16x8;
typedef __attribute__((ext_vector_type(4))) float f32x4;
typedef __attribute__((ext_vector_type(2))) float f32x2;

__device__ inline unsigned short f2bf(float f) {
    unsigned int u = __float_as_uint(f);
    return (unsigned short)((u + 0x7FFFu + ((u >> 16) & 1u)) >> 16);
}
__device__ inline float bf2f(unsigned short u) {
    return __uint_as_float((unsigned int)u << 16);
}
__device__ inline float lrelu(float a) { return (a > 0.f) ? a : NEG * a; }

// ---------------------------------------------------------------------------
// Single-pass bucketing into 512 fine partitions + fused weight transposes.
// ---------------------------------------------------------------------------
__global__ __launch_bounds__(256) void k_bkt(const int* __restrict__ ei,
                                             int* __restrict__ fcur,
                                             unsigned int* __restrict__ fbuf,
                                             const float* __restrict__ W1,
                                             const float* __restrict__ W2,
                                             const float* __restrict__ W3,
                                             unsigned short* __restrict__ Wt1,
                                             unsigned short* __restrict__ Wt2,
                                             unsigned short* __restrict__ Wt3) {
    if (blockIdx.x >= 256) {
        int i = (blockIdx.x - 256) * 256 + threadIdx.x;
        if (i < 32768) {                       // W1: 256 x 128
            int n = i >> 7, k = i & 127;
            Wt1[i] = f2bf(W1[(long)k * 256 + n]);
        } else if (i < 98304) {                // W2: 256 x 256
            int j = i - 32768;
            int n = j >> 8, k = j & 255;
            Wt2[j] = f2bf(W2[(long)k * 256 + n]);
        } else if (i < 114688) {               // W3: 64(pad) x 256
            int j = i - 98304;
            int n = j >> 8, k = j & 255;
            Wt3[j] = (n < OUT_CH) ? f2bf(W3[(long)k * OUT_CH + n]) : (unsigned short)0;
        }
        return;
    }
    __shared__ int lcnt[NFINE], lbase[NFINE], lcur[NFINE];
    int tid = threadIdx.x;
    for (int i = tid; i < NFINE; i += 256) lcnt[i] = 0;
    __syncthreads();
    for (int i = blockIdx.x * 256 + tid; i < ETOT; i += 256 * 256) {
        int d = (i < N_EDGES) ? ei[N_EDGES + i] : (i - N_EDGES);
        atomicAdd(&lcnt[d / NPF], 1);
    }
    __syncthreads();
    for (int i = tid; i < NFINE; i += 256) {
        lbase[i] = atomicAdd(&fcur[i], lcnt[i]);
        lcur[i] = 0;
    }
    __syncthreads();
    for (int i = blockIdx.x * 256 + tid; i < ETOT; i += 256 * 256) {
        int s, d;
        if (i < N_EDGES) { s = ei[i]; d = ei[N_EDGES + i]; }
        else             { s = i - N_EDGES; d = s; }
        int p = d / NPF;
        int off = atomicAdd(&lcur[p], 1);
        fbuf[(long)p * FCAP + lbase[p] + off] = (unsigned int)s | ((unsigned int)d << 16);
    }
}

// Degrees via LDS counting + per-partition padded sum.
__global__ __launch_bounds__(256) void k_deg(const int* __restrict__ fcur,
                                             const unsigned int* __restrict__ fbuf,
                                             int* __restrict__ deg,
                                             int* __restrict__ psum) {
    __shared__ int cnt[NPF];
    __shared__ int tot;
    int f = blockIdx.x;
    int tid = threadIdx.x;
    int n0 = f * NPF;
    int nend = min(n0 + NPF, N_NODES);
    int nn = nend - n0;
    if (tid < NPF) cnt[tid] = 0;
    if (tid == 0) tot = 0;
    __syncthreads();
    int n = fcur[f];
    for (int i = tid; i < n; i += 256)
        atomicAdd(&cnt[(int)(fbuf[(long)f * FCAP + i] >> 16) - n0], 1);
    __syncthreads();
    if (tid < NPF && tid < nn) {
        deg[n0 + tid] = cnt[tid];
        atomicAdd(&tot, (cnt[tid] + 7) & ~7);
    }
    __syncthreads();
    if (tid == 0) psum[f] = tot;
}

// Exclusive scan over 512 partition totals (one block, 512 threads).
__global__ __launch_bounds__(512) void k_pscan(int* __restrict__ psum) {
    __shared__ int sh[NFINE];
    int tid = threadIdx.x;
    int v = psum[tid];
    int x = v;
    sh[tid] = x;
    __syncthreads();
    #pragma unroll
    for (int off = 1; off < NFINE; off <<= 1) {
        int t = (tid >= off) ? sh[tid - off] : 0;
        __syncthreads();
        x += t;
        sh[tid] = x;
        __syncthreads();
    }
    psum[tid] = x - v;
}

// Final: local prefix scan of padded degrees -> start[], scatter, pad fill.
__global__ __launch_bounds__(256) void k_scat(const int* __restrict__ fcur,
                                              const unsigned int* __restrict__ fbuf,
                                              const int* __restrict__ deg,
                                              const int* __restrict__ psum,
                                              int* __restrict__ start,
                                              int* __restrict__ eSrc) {
    __shared__ int sval[128];
    __shared__ int offs[NPF];
    __shared__ int base[NPF];
    int f = blockIdx.x;
    int tid = threadIdx.x;
    int n0 = f * NPF;
    int nend = min(n0 + NPF, N_NODES);
    int nn = nend - n0;
    int pbase = psum[f];

    int pd = 0;
    if (tid < 128) {
        pd = (tid < nn) ? ((deg[n0 + tid] + 7) & ~7) : 0;
        sval[tid] = pd;
    }
    __syncthreads();
    #pragma unroll
    for (int off = 1; off < 128; off <<= 1) {
        int t = 0;
        if (tid < 128 && tid >= off) t = sval[tid - off];
        __syncthreads();
        if (tid < 128) sval[tid] += t;
        __syncthreads();
    }
    if (tid < 128 && tid < nn) {
        int st = pbase + sval[tid] - pd;    // exclusive
        start[n0 + tid] = st;
        offs[tid] = st;
        base[tid] = st;
    }
    __syncthreads();

    int n = fcur[f];
    for (int i = tid; i < n; i += 256) {
        unsigned int u = fbuf[(long)f * FCAP + i];
        int d = (int)(u >> 16);
        int pos = atomicAdd(&offs[d - n0], 1);
        eSrc[pos] = (int)(u & 0xFFFFu);
    }
    __syncthreads();
    if (tid < NPF && tid < nn) {
        int endp = offs[tid];
        int dg = endp - base[tid];
        int stop = base[tid] + ((dg + 7) & ~7);
        for (int k2 = endp; k2 < stop; ++k2) eSrc[k2] = -1;
    }
}

// ---------------------------------------------------------------------------
// bf16 MFMA GEMM with fused attention logits (unchanged).
// ---------------------------------------------------------------------------
#define PITCH 40
template<int BN, int FM, int FN, bool CVT, bool FP8OUT, bool L4>
__global__ __launch_bounds__(256) void k_mfma(const void* __restrict__ Araw,
                                              const unsigned short* __restrict__ Bt,
                                              void* __restrict__ Cout,
                                              const float* __restrict__ a_s,
                                              const float* __restrict__ a_d,
                                              float* __restrict__ als,
                                              float* __restrict__ ald,
                                              int M, int K, int Ncol) {
    __shared__ unsigned short As[128 * PITCH];
    __shared__ unsigned short Bs[BN * PITCH];
    const int WCOLS = BN / (FN * 16);
    int tid = threadIdx.x;
    int wave = tid >> 6, lane = tid & 63;
    int quad = lane >> 4, l16 = lane & 15;
    int wr = wave / WCOLS, wc = wave % WCOLS;
    long row0 = (long)blockIdx.x * 128;
    int col0 = blockIdx.y * BN;

    f32x4 acc[FM][FN] = {};

    for (int k0 = 0; k0 < K; k0 += 32) {
        for (int c = tid; c < 512; c += 256) {
            int r = c >> 2, kp = (c & 3) << 3;
            long gr = row0 + r;
            if (CVT) {
                const float* A32 = (const float*)Araw;
                ushort4 lo = {0,0,0,0}, hi = {0,0,0,0};
                if (gr < M) {
                    float4 v0 = *(const float4*)(A32 + gr * K + k0 + kp);
                    float4 v1 = *(const float4*)(A32 + gr * K + k0 + kp + 4);
                    lo.x = f2bf(v0.x); lo.y = f2bf(v0.y); lo.z = f2bf(v0.z); lo.w = f2bf(v0.w);
                    hi.x = f2bf(v1.x); hi.y = f2bf(v1.y); hi.z = f2bf(v1.z); hi.w = f2bf(v1.w);
                }
                *(ushort4*)(As + r * PITCH + kp) = lo;
                *(ushort4*)(As + r * PITCH + kp + 4) = hi;
            } else {
                const unsigned short* A16 = (const unsigned short*)Araw;
                uint4 v = {0u, 0u, 0u, 0u};
                if (gr < M) v = *(const uint4*)(A16 + gr * K + k0 + kp);
                *(uint4*)(As + r * PITCH + kp) = v;
            }
        }
        for (int c = tid; c < BN * 4; c += 256) {
            int r = c >> 2, kp = (c & 3) << 3;
            uint4 v = *(const uint4*)(Bt + (long)(col0 + r) * K + k0 + kp);
            *(uint4*)(Bs + r * PITCH + kp) = v;
        }
        __syncthreads();
        bf16x8 af[FM], bfr[FN];
        #pragma unroll
        for (int i = 0; i < FM; ++i)
            af[i] = *(const bf16x8*)(As + (wr * FM * 16 + i * 16 + l16) * PITCH + quad * 8);
        #pragma unroll
        for (int j = 0; j < FN; ++j)
            bfr[j] = *(const bf16x8*)(Bs + (wc * FN * 16 + j * 16 + l16) * PITCH + quad * 8);
        #pragma unroll
        for (int i = 0; i < FM; ++i)
            #pragma unroll
            for (int j = 0; j < FN; ++j)
                acc[i][j] = __builtin_amdgcn_mfma_f32_16x16x32_bf16(af[i], bfr[j], acc[i][j], 0, 0, 0);
        __syncthreads();
    }

    // fused logits
    {
        int head = L4 ? (blockIdx.y * WCOLS + wc) : 0;
        float as_v[FN], ad_v[FN];
        #pragma unroll
        for (int j = 0; j < FN; ++j) {
            int cidx = j * 16 + l16;
            if (L4) {
                as_v[j] = a_s[head * 64 + cidx];
                ad_v[j] = a_d[head * 64 + cidx];
            } else {
                as_v[j] = (cidx < OUT_CH) ? a_s[cidx] : 0.f;
                ad_v[j] = (cidx < OUT_CH) ? a_d[cidx] : 0.f;
            }
        }
        #pragma unroll
        for (int i = 0; i < FM; ++i) {
            #pragma unroll
            for (int v = 0; v < 4; ++v) {
                float ps = acc[i][0][v] * as_v[0] + acc[i][1][v] * as_v[1]
                         + acc[i][2][v] * as_v[2] + acc[i][3][v] * as_v[3];
                float pd = acc[i][0][v] * ad_v[0] + acc[i][1][v] * ad_v[1]
                         + acc[i][2][v] * ad_v[2] + acc[i][3][v] * ad_v[3];
                #pragma unroll
                for (int off = 1; off < 16; off <<= 1) {
                    ps += __shfl_xor(ps, off);
                    pd += __shfl_xor(pd, off);
                }
                if (l16 == 0) {
                    long row = row0 + wr * (FM * 16) + i * 16 + quad * 4 + v;
                    if (row < M) {
                        if (L4) { als[row * 4 + head] = ps; ald[row * 4 + head] = pd; }
                        else    { als[row] = ps; ald[row] = pd; }
                    }
                }
            }
        }
    }

    if (FP8OUT) {
        unsigned char* C8 = (unsigned char*)Cout;
        #pragma unroll
        for (int i = 0; i < FM; ++i) {
            #pragma unroll
            for (int v = 0; v < 4; ++v) {
                long row = row0 + wr * FM * 16 + i * 16 + quad * 4 + v;
                if (row < M) {
                    int p01 = __builtin_amdgcn_cvt_pk_fp8_f32(acc[i][0][v], acc[i][1][v], 0, false);
                    int p23 = __builtin_amdgcn_cvt_pk_fp8_f32(acc[i][2][v], acc[i][3][v], 0, false);
                    unsigned char* b = C8 + row * 256 + col0 + wc * (FN * 16) + l16;
                    b[0]  = (unsigned char)(p01 & 0xFF);
                    b[16] = (unsigned char)((p01 >> 8) & 0xFF);
                    b[32] = (unsigned char)(p23 & 0xFF);
                    b[48] = (unsigned char)((p23 >> 8) & 0xFF);
                }
            }
        }
    } else {
        unsigned short* C = (unsigned short*)Cout;
        #pragma unroll
        for (int i = 0; i < FM; ++i) {
            long rowb = row0 + wr * FM * 16 + i * 16 + quad * 4;
            #pragma unroll
            for (int j = 0; j < FN; ++j) {
                int col = col0 + wc * FN * 16 + j * 16 + l16;
                if (col < Ncol) {
                    #pragma unroll
                    for (int v = 0; v < 4; ++v) {
                        long r = rowb + v;
                        if (r < M) C[r * Ncol + col] = f2bf(acc[i][j][v]);
                    }
                }
            }
        }
    }
}

// ---------------------------------------------------------------------------
// Aggregation (4-head), fp8 gather, half-wave edge split, packed f32x2 FMA
// (exact R14 version — proven 44 us).
// ---------------------------------------------------------------------------
__global__ __launch_bounds__(256) void k_agg4(const unsigned char* __restrict__ h8,
                                              const int* __restrict__ start,
                                              const int* __restrict__ deg,
                                              const int* __restrict__ eSrc,
                                              const float* __restrict__ als,
                                              const float* __restrict__ ald,
                                              const float* __restrict__ bias,
                                              unsigned short* __restrict__ out) {
    __shared__ float wbuf[4][CAP * 4];
    __shared__ int   sbuf[4][CAP];
    int wid = threadIdx.x >> 6;
    int node = (blockIdx.x * blockDim.x + threadIdx.x) >> 6;
    int lane = threadIdx.x & 63;
    if (node >= N_NODES) return;
    int st = start[node];
    int dgp = (deg[node] + 7) & ~7;
    const int* ep = eSrc + st;

    // ---- phase 1: weights into LDS ----
    int l16 = lane & 15, headw = lane >> 4;
    float aldd4 = ald[node * 4 + headw];
    int ncap = (dgp < CAP) ? dgp : CAP;
    for (int c = 0; c < ncap; c += 16) {
        int slot = c + l16;
        bool ok = (slot < ncap);
        int raw = ok ? ep[slot] : -1;
        int ss = (raw < 0) ? 0 : raw;
        float a = als[(long)ss * 4 + headw] + aldd4;
        float w = (raw < 0) ? 0.f : __expf(lrelu(a));
        if (ok) {
            wbuf[wid][slot * 4 + headw] = w;
            if (headw == 0) sbuf[wid][slot] = ss;
        }
    }

    // ---- phase 2: half-wave per edge, 8 ch/lane (fp8), packed FMA ----
    int half = lane >> 5;
    int hl = lane & 31;
    int head8 = hl >> 3;
    float den = 0.f;
    f32x2 acc2[4] = {};

    int ncpair = ncap >> 1;
    int jA = 0, jB = ncpair - 4;

    auto do_pairs = [&](int p0, int p1, int p2, int p3) {
        int slot[4] = {p0 * 2 + half, p1 * 2 + half, p2 * 2 + half, p3 * 2 + half};
        int s[4];
        float w[4];
        #pragma unroll
        for (int u = 0; u < 4; ++u) {
            s[u] = sbuf[wid][slot[u]];
            w[u] = wbuf[wid][slot[u] * 4 + head8];
        }
        uint2 hv[4];
        #pragma unroll
        for (int u = 0; u < 4; ++u)
            hv[u] = *(const uint2*)(h8 + (long)s[u] * 256 + hl * 8);
        #pragma unroll
        for (int u = 0; u < 4; ++u) {
            den += w[u];
            f32x2 w2; w2.x = w[u]; w2.y = w[u];
            acc2[0] += w2 * __builtin_amdgcn_cvt_pk_f32_fp8((int)hv[u].x, false);
            acc2[1] += w2 * __builtin_amdgcn_cvt_pk_f32_fp8((int)hv[u].x, true);
            acc2[2] += w2 * __builtin_amdgcn_cvt_pk_f32_fp8((int)hv[u].y, false);
            acc2[3] += w2 * __builtin_amdgcn_cvt_pk_f32_fp8((int)hv[u].y, true);
        }
    };

    while (jA < jB) {
        do_pairs(jA, jA + 1, jB, jB + 1);
        do_pairs(jA + 2, jA + 3, jB + 2, jB + 3);
        jA += 8; jB -= 8;
        // note: jA/jB advanced by 8 pairs total per loop (4 front + 4 back)
        jA -= 4; jB += 4;
    }
    if (jA == jB) {
        do_pairs(jA, jA + 1, jA + 2, jA + 3);
    }

    if (dgp > ncap) {
        float aldd8 = ald[node * 4 + head8];
        for (int j = ncap; j < dgp; j += 2) {
            int raw = ep[j + half];
            int ss = (raw < 0) ? 0 : raw;
            float w = (raw < 0) ? 0.f : __expf(lrelu(als[(long)ss * 4 + head8] + aldd8));
            uint2 hv = *(const uint2*)(h8 + (long)ss * 256 + hl * 8);
            den += w;
            f32x2 w2; w2.x = w; w2.y = w;
            acc2[0] += w2 * __builtin_amdgcn_cvt_pk_f32_fp8((int)hv.x, false);
            acc2[1] += w2 * __builtin_amdgcn_cvt_pk_f32_fp8((int)hv.x, true);
            acc2[2] += w2 * __builtin_amdgcn_cvt_pk_f32_fp8((int)hv.y, false);
            acc2[3] += w2 * __builtin_amdgcn_cvt_pk_f32_fp8((int)hv.y, true);
        }
    }

    den += __shfl_xor(den, 32);
    #pragma unroll
    for (int c = 0; c < 4; ++c) {
        acc2[c].x += __shfl_xor(acc2[c].x, 32);
        acc2[c].y += __shfl_xor(acc2[c].y, 32);
    }

    if (half == 0) {
        float inv = 1.f / den;
        int cb = hl * 8;
        float4 b0 = *(const float4*)(bias + cb);
        float4 b1 = *(const float4*)(bias + cb + 4);
        float v0 = fmaxf(acc2[0].x * inv + b0.x, 0.f);
        float v1 = fmaxf(acc2[0].y * inv + b0.y, 0.f);
        float v2 = fmaxf(acc2[1].x * inv + b0.z, 0.f);
        float v3 = fmaxf(acc2[1].y * inv + b0.w, 0.f);
        float v4 = fmaxf(acc2[2].x * inv + b1.x, 0.f);
        float v5 = fmaxf(acc2[2].y * inv + b1.y, 0.f);
        float v6 = fmaxf(acc2[3].x * inv + b1.z, 0.f);
        float v7 = fmaxf(acc2[3].y * inv + b1.w, 0.f);
        uint4 o;
        o.x = (unsigned int)f2bf(v0) | ((unsigned int)f2bf(v1) << 16);
        o.y = (unsigned int)f2bf(v2) | ((unsigned int)f2bf(v3) << 16);
        o.z = (unsigned int)f2bf(v4) | ((unsigned int)f2bf(v5) << 16);
        o.w = (unsigned int)f2bf(v6) | ((unsigned int)f2bf(v7) << 16);
        *(uint4*)(out + (long)node * 256 + cb) = o;
    }
}

// ---------------------------------------------------------------------------
// Final layer agg (unchanged from R14).
// ---------------------------------------------------------------------------
__global__ __launch_bounds__(256) void k_agg1(const unsigned short* __restrict__ h,
                                              const int* __restrict__ start,
                                              const int* __restrict__ deg,
                                              const int* __restrict__ eSrc,
                                              const float* __restrict__ als,
                                              const float* __restrict__ ald,
                                              const float* __restrict__ bias,
                                              float* __restrict__ out) {
    int node = (blockIdx.x * blockDim.x + threadIdx.x) >> 6;
    int lane = threadIdx.x & 63;
    if (node >= N_NODES) return;
    int q = lane >> 4, r = lane & 15;
    bool act = (r < 10);
    int st = start[node];
    int dgp = (deg[node] + 7) & ~7;
    const int* ep = eSrc + st;
    float aldd = ald[node];

    float den = 0.f;
    float4 acc = {0.f, 0.f, 0.f, 0.f};

    int j = 0;
    for (; j + 16 <= dgp; j += 16) {
        int base = j + q * 4;
        int s[4];
        float w[4];
        #pragma unroll
        for (int u = 0; u < 4; ++u) s[u] = ep[base + u];
        #pragma unroll
        for (int u = 0; u < 4; ++u) {
            int raw = s[u];
            int ss = (raw < 0) ? 0 : raw;
            w[u] = (raw < 0) ? 0.f : __expf(lrelu(als[ss] + aldd));
            s[u] = ss;
        }
        ushort4 hh[4];
        #pragma unroll
        for (int u = 0; u < 4; ++u) {
            ushort4 t = {0, 0, 0, 0};
            if (act) t = *(const ushort4*)(h + (long)s[u] * OUT_CH + r * 4);
            hh[u] = t;
        }
        #pragma unroll
        for (int u = 0; u < 4; ++u) {
            den += w[u];
            acc.x += w[u] * bf2f(hh[u].x);
            acc.y += w[u] * bf2f(hh[u].y);
            acc.z += w[u] * bf2f(hh[u].z);
            acc.w += w[u] * bf2f(hh[u].w);
        }
    }
    if (j < dgp) {
        int base = j + q * 2;
        int s[2];
        float w[2];
        #pragma unroll
        for (int u = 0; u < 2; ++u) s[u] = ep[base + u];
        #pragma unroll
        for (int u = 0; u < 2; ++u) {
            int raw = s[u];
            int ss = (raw < 0) ? 0 : raw;
            w[u] = (raw < 0) ? 0.f : __expf(lrelu(als[ss] + aldd));
            s[u] = ss;
        }
        ushort4 hh[2];
        #pragma unroll
        for (int u = 0; u < 2; ++u) {
            ushort4 t = {0, 0, 0, 0};
            if (act) t = *(const ushort4*)(h + (long)s[u] * OUT_CH + r * 4);
            hh[u] = t;
        }
        #pragma unroll
        for (int u = 0; u < 2; ++u) {
            den += w[u];
            acc.x += w[u] * bf2f(hh[u].x);
            acc.y += w[u] * bf2f(hh[u].y);
            acc.z += w[u] * bf2f(hh[u].z);
            acc.w += w[u] * bf2f(hh[u].w);
        }
    }

    #pragma unroll
    for (int off = 16; off < 64; off <<= 1) {
        acc.x += __shfl_xor(acc.x, off);
        acc.y += __shfl_xor(acc.y, off);
        acc.z += __shfl_xor(acc.z, off);
        acc.w += __shfl_xor(acc.w, off);
        den   += __shfl_xor(den, off);
    }
    float inv = 1.f / den;
    float4 bv = {0.f, 0.f, 0.f, 0.f};
    if (act) bv = *(const float4*)(bias + r * 4);
    float4 v;
    v.x = acc.x * inv + bv.x;
    v.y = acc.y * inv + bv.y;
    v.z = acc.z * inv + bv.z;
    v.w = acc.w * inv + bv.w;
    float mx = act ? fmaxf(fmaxf(v.x, v.y), fmaxf(v.z, v.w)) : -INFINITY;
    #pragma unroll
    for (int off = 1; off < 16; off <<= 1) mx = fmaxf(mx, __shfl_xor(mx, off));
    float sum = act ? (__expf(v.x - mx) + __expf(v.y - mx) + __expf(v.z - mx) + __expf(v.w - mx)) : 0.f;
    #pragma unroll
    for (int off = 1; off < 16; off <<= 1) sum += __shfl_xor(sum, off);
    float lse = mx + logf(sum);
    if (q == 0 && act) {
        float4 o;
        o.x = v.x - lse;
        o.y = v.y - lse;
        o.z = v.z - lse;
        o.w = v.w - lse;
        *(float4*)(out + (long)node * OUT_CH + r * 4) = o;
    }
}

// ---------------------------------------------------------------------------
extern "C" void kernel_launch(void* const* d_in, const int* in_sizes, int n_in,
                              void* d_out, int out_size, void* d_ws, size_t ws_size,
                              hipStream_t stream) {
    (void)in_sizes; (void)n_in; (void)out_size; (void)ws_size;
    const float* x   = (const float*)d_in[0];
    const int*   ei  = (const int*)d_in[1];
    const float* W1  = (const float*)d_in[2];
    const float* as1 = (const float*)d_in[3];
    const float* ad1 = (const float*)d_in[4];
    const float* b1  = (const float*)d_in[5];
    const float* W2  = (const float*)d_in[6];
    const float* as2 = (const float*)d_in[7];
    const float* ad2 = (const float*)d_in[8];
    const float* b2  = (const float*)d_in[9];
    const float* W3  = (const float*)d_in[10];
    const float* as3 = (const float*)d_in[11];
    const float* ad3 = (const float*)d_in[12];
    const float* b3  = (const float*)d_in[13];
    float* out = (float*)d_out;

    char* p = (char*)d_ws;
    auto alloc = [&](size_t b) { char* r = p; p += (b + 255) & ~(size_t)255; return r; };
    int*   deg   = (int*)alloc((size_t)N_NODES * 4);
    int*   start = (int*)alloc((size_t)N_NODES * 4);
    int*   psum  = (int*)alloc((size_t)NFINE * 4);
    int*   fcur  = (int*)alloc((size_t)NFINE * 4);
    unsigned int* fbuf = (unsigned int*)alloc((size_t)NFINE * FCAP * 4);
    int*   eSrc  = (int*)alloc((size_t)EPAD_MAX * 4);
    float* als   = (float*)alloc((size_t)N_NODES * 4 * 4);
    float* ald   = (float*)alloc((size_t)N_NODES * 4 * 4);
    unsigned char*  hA8  = (unsigned char*)alloc((size_t)N_NODES * 256);
    unsigned short* hBbf = (unsigned short*)alloc((size_t)N_NODES * 256 * 2);
    unsigned short* h3bf = (unsigned short*)alloc((size_t)N_NODES * OUT_CH * 2);
    unsigned short* Wt1  = (unsigned short*)alloc((size_t)256 * IN_CH * 2);
    unsigned short* Wt2  = (unsigned short*)alloc((size_t)256 * 256 * 2);
    unsigned short* Wt3  = (unsigned short*)alloc((size_t)64 * 256 * 2);

    const int WB = (N_NODES + 3) / 4;
    const int MB = (N_NODES + 127) / 128;

    // ---- CSR build + weight transpose ----
    hipMemsetAsync(fcur, 0, (size_t)NFINE * 4, stream);
    k_bkt<<<256 + 448, 256, 0, stream>>>(ei, fcur, fbuf, W1, W2, W3, Wt1, Wt2, Wt3);
    k_deg<<<NFINE, 256, 0, stream>>>(fcur, fbuf, deg, psum);
    k_pscan<<<1, NFINE, 0, stream>>>(psum);
    k_scat<<<NFINE, 256, 0, stream>>>(fcur, fbuf, deg, psum, start, eSrc);

    // ---- layer 1 (fp32 in, fp8 out, fused logits) ----
    k_mfma<128, 4, 4, true, true, true><<<dim3(MB, 2), 256, 0, stream>>>(
        x, Wt1, hA8, as1, ad1, als, ald, N_NODES, IN_CH, 256);
    k_agg4<<<WB, 256, 0, stream>>>(hA8, start, deg, eSrc, als, ald, b1, hBbf);

    // ---- layer 2 (bf16 in, fp8 out, fused logits) ----
    k_mfma<128, 4, 4, false, true, true><<<dim3(MB, 2), 256, 0, stream>>>(
        hBbf, Wt2, hA8, as2, ad2, als, ald, N_NODES, 256, 256);
    k_agg4<<<WB, 256, 0, stream>>>(hA8, start, deg, eSrc, als, ald, b2, hBbf);

    // ---- layer 3 (bf16 in, bf16 out, fused single-head logits) ----
    k_mfma<64, 2, 4, false, false, false><<<dim3(MB, 1), 256, 0, stream>>>(
        hBbf, Wt3, h3bf, as3, ad3, als, ald, N_NODES, 256, OUT_CH);
    k_agg1<<<WB, 256, 0, stream>>>(h3bf, start, deg, eSrc, als, ald, b3, out);
}